// Round 10
// baseline (935.133 us; speedup 1.0000x reference)
//
#include <hip/hip_runtime.h>
#include <math.h>

#define S_    10
#define C_    48
#define HWD   64
#define M_    512
#define PADK  4
#define PAIRS 20           // S_ * N(=2)
#define YPITCH 516         // LDS pitch (516%32=4 -> only 2-way bank alias = free)
#define REP   32           // diagnostic repeat factor (this round only)

// Compact gathered layout: G[(s*96 + 2*c + n)*512 + m]
// ws layout (float offsets)
#define OFF_GY  0
#define OFF_GX  491520                    // 10*48*2*512
#define OFF_CM  (2 * 491520)              // colmax (uint-encoded floats), 10240
#define OFF_MU  (OFF_CM + PAIRS * M_)     // 480 floats
#define OFF_CNT (OFF_MU + 480)            // 20 uint pair-arrival counters
#define OFF_ALL (OFF_CNT + 20)            // 1 uint global pair-done counter
#define OFF_PL  (OFF_ALL + 1)             // 20 float pair losses
#define OFF_NY  1048576                   // normalized y (out-of-place)
#define OFF_NX  (OFF_NY + 491520)         // normalized x; total ~8.1 MB < ws

__device__ __forceinline__ int gidx(int n, int c, int h, int w, int d) {
  return (((n * C_ + c) * HWD + h) * HWD + w) * HWD + d;
}

// opaque zero: defeats cross-rep load hoisting / identical-store collapsing
__device__ __forceinline__ int launder_zero() {
  int z0 = 0;
  asm volatile("" : "+v"(z0));
  return z0;
}

// ---- kernel 1: gather x,y -> compact ws; fold y channel-mean (xREP) -------
__global__ void k_gather(const float* __restrict__ x, const float* __restrict__ y,
                         const int* __restrict__ hi, const int* __restrict__ wi,
                         const int* __restrict__ di, float* __restrict__ ws) {
  int b = blockIdx.x, t = threadIdx.x;
  int lane = t & 63, wv = t >> 6;
  __shared__ float red[4];
  int which = b >= 480;                              // 0 = y, 1 = x
  int r = which ? b - 480 : b;
  int s = r / C_, c = r % C_;
  const float* src = which ? x : y;
  int h0 = hi[s] - PADK, w0 = wi[s] - PADK, d0 = di[s] - PADK;

  for (int rep = 0; rep < REP; ++rep) {
    __syncthreads();                                 // protect red across reps
    int z0 = launder_zero();
    if (b < 40) ws[OFF_CM + b * 256 + t + z0] = 0.f; // zero colmax (10240)
    if (b == 40 && t < 41) ws[OFF_CNT + t + z0] = 0.f;
    float* dst = ws + (which ? OFF_GX : OFF_GY) + (s * 96 + 2 * c) * 512 + z0;
    float sum = 0.f;
#pragma unroll
    for (int j = 0; j < 4; ++j) {
      int i = t + 256 * j;             // 0..1023 over (n,m)
      int n = i >> 9, m = i & 511;
      float v = src[gidx(n, c, h0 + (m >> 6), w0 + ((m >> 3) & 7), d0 + (m & 7)) + z0];
      dst[n * 512 + m] = v;            // coalesced compact store
      sum += v;
    }
    if (!which) {                      // block-uniform branch
#pragma unroll
      for (int off = 32; off; off >>= 1) sum += __shfl_xor(sum, off);
      if (lane == 0) red[wv] = sum;
      __syncthreads();
      if (t == 0)
        ws[OFF_MU + s * C_ + c + z0] =
            (red[0] + red[1] + red[2] + red[3]) * (1.0f / 1024.0f);
    }
  }
}

// ---- kernel 2: center + L2-normalize, OUT-OF-PLACE GY/GX -> NY/NX (xREP) --
__global__ void k_norm2(float* __restrict__ ws) {
  int g = blockIdx.x * 256 + threadIdx.x;   // 0..81919
  int col = g >> 2;                         // 0..20479
  int q = threadIdx.x & 3;                  // channel quarter
  int which = col >= 10240;                 // 0 = y, 1 = x
  int cix = which ? col - 10240 : col;
  int pair = cix >> 9, m = cix & 511;
  int s = pair >> 1, n = pair & 1;
  int rdoff = (which ? OFF_GX : OFF_GY) + (s * 96 + n) * 512 + m;
  int wroff = (which ? OFF_NX : OFF_NY) + (s * 96 + n) * 512 + m;
  const float* mus = ws + OFF_MU + s * C_;
  int c0 = q * 12;

  for (int rep = 0; rep < REP; ++rep) {
    int z0 = launder_zero();
    float v[12], ss = 0.f;
#pragma unroll
    for (int j = 0; j < 12; ++j) {
      v[j] = ws[rdoff + (c0 + j) * 1024 + z0] - mus[c0 + j];
      ss += v[j] * v[j];
    }
    ss += __shfl_xor(ss, 1);           // combine 4 quarters (aligned group)
    ss += __shfl_xor(ss, 2);
    float sc = 1.0f / fmaxf(sqrtf(ss), 1e-12f);
#pragma unroll
    for (int j = 0; j < 12; ++j) ws[wroff + (c0 + j) * 1024 + z0] = v[j] * sc;
  }
}

// ---- kernel 3: dist + row-softmax + column-max + fused final (xREP) -------
__global__ __launch_bounds__(256, 2) void k_main(float* __restrict__ ws,
                                                 float* __restrict__ out) {
  int b = blockIdx.x;
  int pair = b >> 4, tile = b & 15;
  int s = pair >> 1, n = pair & 1;
  int t = threadIdx.x, lane = t & 63, wv = t >> 6;

  __shared__ float xl[C_ * 32];        // x tile: [c][row] (32 rows)
  __shared__ float yl[12 * YPITCH];    // y chunk: [c_rel][p]
  __shared__ unsigned arr;
  __shared__ float red[4];
  __shared__ int lastflag;

  for (int rep = 0; rep < REP; ++rep) {
    __syncthreads();                   // protect xl/red/arr across reps
    int z0 = launder_zero();
    const float* xsrc = ws + OFF_NX + (s * 96 + n) * 512 + tile * 32 + z0;
#pragma unroll
    for (int i = 0; i < 2; ++i) {
      int li = t + 256 * i;            // 384 float4s
      if (li < 384) {
        int c = li >> 3, r4 = (li & 7) << 2;
        *(float4*)(xl + c * 32 + r4) = *(const float4*)(xsrc + c * 1024 + r4);
      }
    }

    float acc[8][8];
#pragma unroll
    for (int r = 0; r < 8; ++r)
#pragma unroll
      for (int k = 0; k < 8; ++k) acc[r][k] = 0.f;

    const float* ysrc = ws + OFF_NY + (s * 96 + n) * 512 + z0;
    for (int chunk = 0; chunk < 4; ++chunk) {
      __syncthreads();
#pragma unroll
      for (int i = 0; i < 6; ++i) {    // 12 channels x 512 = 1536 float4s
        int li = t + 256 * i;
        int cr = li >> 7, p4 = (li & 127) << 2;
        *(float4*)(yl + cr * YPITCH + p4) =
            *(const float4*)(ysrc + (chunk * 12 + cr) * 1024 + p4);
      }
      __syncthreads();
#pragma unroll
      for (int cr = 0; cr < 12; ++cr) {
        float yv[8];
#pragma unroll
        for (int k = 0; k < 8; ++k) yv[k] = yl[cr * YPITCH + lane + 64 * k];
        int c = chunk * 12 + cr;
#pragma unroll
        for (int r4 = 0; r4 < 2; ++r4) {
          float4 xv = *(const float4*)(xl + c * 32 + wv * 8 + r4 * 4);
#pragma unroll
          for (int k = 0; k < 8; ++k) {
            acc[r4 * 4 + 0][k] += xv.x * yv[k];
            acc[r4 * 4 + 1][k] += xv.y * yv[k];
            acc[r4 * 4 + 2][k] += xv.z * yv[k];
            acc[r4 * 4 + 3][k] += xv.w * yv[k];
          }
        }
      }
    }

    float cmax[8];
#pragma unroll
    for (int k = 0; k < 8; ++k) cmax[k] = 0.f;
#pragma unroll
    for (int r = 0; r < 8; ++r) {
      float dmin = 3.4e38f;
#pragma unroll
      for (int k = 0; k < 8; ++k) {
        float d = 1.0f - acc[r][k];
        acc[r][k] = d;
        dmin = fminf(dmin, d);
      }
#pragma unroll
      for (int off = 32; off; off >>= 1) dmin = fminf(dmin, __shfl_xor(dmin, off));
      float inv = 2.0f / (dmin + 1e-5f);  // logits <= 2, no overflow
      float e[8], sm = 0.f;
#pragma unroll
      for (int k = 0; k < 8; ++k) {
        e[k] = __expf(2.0f - acc[r][k] * inv);
        sm += e[k];
      }
#pragma unroll
      for (int off = 32; off; off >>= 1) sm += __shfl_xor(sm, off);
      float rs = 1.0f / sm;
#pragma unroll
      for (int k = 0; k < 8; ++k) cmax[k] = fmaxf(cmax[k], e[k] * rs);
    }
    unsigned* cmu = (unsigned*)(ws + OFF_CM) + pair * M_;
#pragma unroll
    for (int k = 0; k < 8; ++k)
      atomicMax(&cmu[lane + 64 * k], __float_as_uint(cmax[k]));

    // fused final: fires only in the rep where this pair's 16th block lands
    __threadfence();
    if (t == 0) arr = atomicAdd((unsigned*)(ws + OFF_CNT) + pair, 1u);
    __syncthreads();
    if (arr == 15) {
      float sum = __uint_as_float(atomicOr(&cmu[t], 0u)) +
                  __uint_as_float(atomicOr(&cmu[t + 256], 0u));
#pragma unroll
      for (int off = 32; off; off >>= 1) sum += __shfl_xor(sum, off);
      if (lane == 0) red[wv] = sum;
      if (t == 0) lastflag = 0;
      __syncthreads();
      if (t == 0) {
        float tot = red[0] + red[1] + red[2] + red[3];
        float loss = -logf(tot * (1.0f / 512.0f) + 1e-5f);
        atomicExch((unsigned*)(ws + OFF_PL) + pair, __float_as_uint(loss));
        __threadfence();
        unsigned d = atomicAdd((unsigned*)(ws + OFF_ALL), 1u);
        if (d == PAIRS - 1) lastflag = 1;
      }
      __syncthreads();
      if (lastflag && t < 32) {        // parallel 20-loss readback
        float v = (t < PAIRS)
                      ? __uint_as_float(atomicOr((unsigned*)(ws + OFF_PL) + t, 0u))
                      : 0.f;
#pragma unroll
        for (int off = 16; off; off >>= 1) v += __shfl_xor(v, off);
        if (t == 0) out[0] = v * (1.0f / (float)PAIRS);
      }
    }
  }
}

extern "C" void kernel_launch(void* const* d_in, const int* in_sizes, int n_in,
                              void* d_out, int out_size, void* d_ws, size_t ws_size,
                              hipStream_t stream) {
  const float* x = (const float*)d_in[0];
  const float* y = (const float*)d_in[1];
  const int* hi = (const int*)d_in[2];
  const int* wi = (const int*)d_in[3];
  const int* di = (const int*)d_in[4];
  float* ws = (float*)d_ws;
  float* out = (float*)d_out;

  k_gather<<<960, 256, 0, stream>>>(x, y, hi, wi, di, ws);
  k_norm2<<<320, 256, 0, stream>>>(ws);
  k_main<<<PAIRS * 16, 256, 0, stream>>>(ws, out);
}

// Round 11
// 66.960 us; speedup vs baseline: 13.9656x; 13.9656x over previous
//
#include <hip/hip_runtime.h>
#include <math.h>

#define S_    10
#define C_    48
#define HWD   64
#define M_    512
#define PADK  4
#define PAIRS 20           // S_ * N(=2)
#define YPITCH 516         // LDS pitch (516%32=4 -> only 2-way bank alias = free)

// Compact gathered layout: G[(s*96 + 2*c + n)*512 + m]
// ws layout (float offsets)
#define OFF_GY  0
#define OFF_GX  491520                    // 10*48*2*512
#define OFF_CM  (2 * 491520)              // colmax (uint-encoded floats), 10240
#define OFF_MU  (OFF_CM + PAIRS * M_)     // 480 floats (holds SUM; /1024 at use)
#define OFF_CNT (OFF_MU + 480)            // 20 uint pair-arrival counters
#define OFF_ALL (OFF_CNT + 20)            // 1 uint global pair-done counter
#define OFF_PL  (OFF_ALL + 1)             // 20 float pair losses
#define ZERO_N  (10240 + 480 + 20 + 1 + 20)   // OFF_CM..OFF_PL contiguous

__device__ __forceinline__ int gidx(int n, int c, int h, int w, int d) {
  return (((n * C_ + c) * HWD + h) * HWD + w) * HWD + d;
}

// ---- kernel 1: gather x,y -> compact ws; y channel-sums via 2x atomicAdd --
// 1920 blocks x 256 thr; block = (slice, half); 2 loads in flight/thread,
// 7.5 waves/SIMD (vs 3.75 in R9) for the latency-bound scattered read.
// Exactly 2 float atomicAdds per mu cell: a+b == b+a -> deterministic.
__global__ void k_gather(const float* __restrict__ x, const float* __restrict__ y,
                         const int* __restrict__ hi, const int* __restrict__ wi,
                         const int* __restrict__ di, float* __restrict__ ws) {
  int b = blockIdx.x, t = threadIdx.x;
  int lane = t & 63, wv = t >> 6;
  int slice = b >> 1, half = b & 1;
  int which = slice >= 480;                          // 0 = y, 1 = x
  int r = which ? slice - 480 : slice;
  int s = r / C_, c = r % C_;
  const float* src = which ? x : y;
  int h0 = hi[s] - PADK, w0 = wi[s] - PADK, d0 = di[s] - PADK;
  float* dst = ws + (which ? OFF_GX : OFF_GY) + (s * 96 + 2 * c) * 512 + half * 512;
  float sum = 0.f;
#pragma unroll
  for (int j = 0; j < 2; ++j) {
    int m = t + 256 * j;               // n = half, m in [0,512)
    float v = src[gidx(half, c, h0 + (m >> 6), w0 + ((m >> 3) & 7), d0 + (m & 7))];
    dst[m] = v;                        // coalesced compact store
    sum += v;
  }
  if (!which) {                        // block-uniform branch
    __shared__ float red[4];
#pragma unroll
    for (int off = 32; off; off >>= 1) sum += __shfl_xor(sum, off);
    if (lane == 0) red[wv] = sum;
    __syncthreads();
    if (t == 0)
      atomicAdd(ws + OFF_MU + s * C_ + c, red[0] + red[1] + red[2] + red[3]);
  }
}

// ---- kernel 2: center + L2-normalize IN PLACE on the compact buffer -------
// 320 blocks x 256 thr; 4 lanes per column (12 channels each). L2-resident.
__global__ void k_norm2(float* __restrict__ ws) {
  int g = blockIdx.x * 256 + threadIdx.x;   // 0..81919
  int col = g >> 2;                         // 0..20479
  int q = threadIdx.x & 3;                  // channel quarter
  int which = col >= 10240;                 // 0 = y, 1 = x
  int cix = which ? col - 10240 : col;
  int pair = cix >> 9, m = cix & 511;
  int s = pair >> 1, n = pair & 1;
  float* base = ws + (which ? OFF_GX : OFF_GY) + (s * 96 + n) * 512 + m;
  const float* mus = ws + OFF_MU + s * C_;
  int c0 = q * 12;
  float v[12];
  float ss = 0.f;
#pragma unroll
  for (int j = 0; j < 12; ++j) {
    v[j] = base[(c0 + j) * 1024] - mus[c0 + j] * (1.0f / 1024.0f);
    ss += v[j] * v[j];
  }
  // combine the 4 quarters of this column (aligned 4-lane group)
  ss += __shfl_xor(ss, 1);
  ss += __shfl_xor(ss, 2);
  float sc = 1.0f / fmaxf(sqrtf(ss), 1e-12f);
#pragma unroll
  for (int j = 0; j < 12; ++j) base[(c0 + j) * 1024] = v[j] * sc;
}

// one 64-FMA block: rows 0-7 of this wave x 8 p-cols, channel c.
// per-accumulator FMA order identical to R9 (one FMA per (c)) -> bit-identical.
#define FMA_BLOCK(YV, cidx)                                          \
  do {                                                               \
    float4 xv0 = *(const float4*)(xl + (cidx) * 32 + wv * 8);        \
    float4 xv1 = *(const float4*)(xl + (cidx) * 32 + wv * 8 + 4);    \
    _Pragma("unroll") for (int k = 0; k < 8; ++k) {                  \
      acc[0][k] += xv0.x * YV[k]; acc[1][k] += xv0.y * YV[k];        \
      acc[2][k] += xv0.z * YV[k]; acc[3][k] += xv0.w * YV[k];        \
      acc[4][k] += xv1.x * YV[k]; acc[5][k] += xv1.y * YV[k];        \
      acc[6][k] += xv1.z * YV[k]; acc[7][k] += xv1.w * YV[k];        \
    }                                                                \
  } while (0)

// ---- kernel 3: dist + row-softmax + column-max + fused final --------------
// 320 blocks x 256 thr; block = (pair, tile of 32 rows); 8 rows/wave.
// Double-buffered y staging (issue-early / write-late) + yv register
// double-buffer so LDS & global latency hide under the FMA stream.
__global__ __launch_bounds__(256, 2) void k_main(float* __restrict__ ws,
                                                 float* __restrict__ out) {
  int b = blockIdx.x;
  int pair = b >> 4, tile = b & 15;
  int s = pair >> 1, n = pair & 1;
  int t = threadIdx.x, lane = t & 63, wv = t >> 6;

  __shared__ float xl[C_ * 32];        // x tile: [c][row] (32 rows)
  __shared__ float yl0[12 * YPITCH];   // y chunk double-buffer
  __shared__ float yl1[12 * YPITCH];

  const float* xsrc = ws + OFF_GX + (s * 96 + n) * 512 + tile * 32;
  const float* ysrc = ws + OFF_GY + (s * 96 + n) * 512;

  // prologue: stage x tile + y chunk 0
#pragma unroll
  for (int i = 0; i < 2; ++i) {
    int li = t + 256 * i;              // 384 float4s
    if (li < 384) {
      int c = li >> 3, r4 = (li & 7) << 2;
      *(float4*)(xl + c * 32 + r4) = *(const float4*)(xsrc + c * 1024 + r4);
    }
  }
  {
    float4 stg[6];
#pragma unroll
    for (int i = 0; i < 6; ++i) {
      int li = t + 256 * i, cr = li >> 7, p4 = (li & 127) << 2;
      stg[i] = *(const float4*)(ysrc + cr * 1024 + p4);
    }
#pragma unroll
    for (int i = 0; i < 6; ++i) {
      int li = t + 256 * i, cr = li >> 7, p4 = (li & 127) << 2;
      *(float4*)(yl0 + cr * YPITCH + p4) = stg[i];
    }
  }

  float acc[8][8];
#pragma unroll
  for (int r = 0; r < 8; ++r)
#pragma unroll
    for (int k = 0; k < 8; ++k) acc[r][k] = 0.f;

#pragma unroll
  for (int chunk = 0; chunk < 4; ++chunk) {
    float* ycur = (chunk & 1) ? yl1 : yl0;
    float* ynxt = (chunk & 1) ? yl0 : yl1;
    float4 stg[6];
    if (chunk < 3) {                   // issue next-chunk loads EARLY
#pragma unroll
      for (int i = 0; i < 6; ++i) {
        int li = t + 256 * i, cr = li >> 7, p4 = (li & 127) << 2;
        stg[i] = *(const float4*)(ysrc + ((chunk + 1) * 12 + cr) * 1024 + p4);
      }
    }
    __syncthreads();                   // ycur fully written (prev iter / prologue)

    // compute chunk from ycur with yv register double-buffer
    float yva[8], yvb[8];
#pragma unroll
    for (int k = 0; k < 8; ++k) yva[k] = ycur[lane + 64 * k];
#pragma unroll
    for (int crp = 0; crp < 6; ++crp) {
      int cr0 = 2 * crp, cr1 = cr0 + 1;
#pragma unroll
      for (int k = 0; k < 8; ++k) yvb[k] = ycur[cr1 * YPITCH + lane + 64 * k];
      FMA_BLOCK(yva, chunk * 12 + cr0);
      if (crp < 5) {
#pragma unroll
        for (int k = 0; k < 8; ++k)
          yva[k] = ycur[(cr0 + 2) * YPITCH + lane + 64 * k];
      }
      FMA_BLOCK(yvb, chunk * 12 + cr1);
    }

    if (chunk < 3) {                   // write next chunk LATE (loads landed)
#pragma unroll
      for (int i = 0; i < 6; ++i) {
        int li = t + 256 * i, cr = li >> 7, p4 = (li & 127) << 2;
        *(float4*)(ynxt + cr * YPITCH + p4) = stg[i];
      }
    }
  }

  // epilogue: per row min -> softmax over p -> column-max accumulate
  float cmax[8];
#pragma unroll
  for (int k = 0; k < 8; ++k) cmax[k] = 0.f;
#pragma unroll
  for (int r = 0; r < 8; ++r) {
    float dmin = 3.4e38f;
#pragma unroll
    for (int k = 0; k < 8; ++k) {
      float d = 1.0f - acc[r][k];
      acc[r][k] = d;
      dmin = fminf(dmin, d);
    }
#pragma unroll
    for (int off = 32; off; off >>= 1) dmin = fminf(dmin, __shfl_xor(dmin, off));
    float inv = 2.0f / (dmin + 1e-5f);  // logits <= 2, no overflow
    float e[8], sm = 0.f;
#pragma unroll
    for (int k = 0; k < 8; ++k) {
      e[k] = __expf(2.0f - acc[r][k] * inv);
      sm += e[k];
    }
#pragma unroll
    for (int off = 32; off; off >>= 1) sm += __shfl_xor(sm, off);
    float rs = 1.0f / sm;
#pragma unroll
    for (int k = 0; k < 8; ++k) cmax[k] = fmaxf(cmax[k], e[k] * rs);
  }
  unsigned* cmu = (unsigned*)(ws + OFF_CM) + pair * M_;
#pragma unroll
  for (int k = 0; k < 8; ++k)
    atomicMax(&cmu[lane + 64 * k], __float_as_uint(cmax[k]));

  // ---- fused final: last block per pair reduces; last pair writes out ----
  __threadfence();
  __shared__ unsigned arr;
  __shared__ float red[4];
  __shared__ int lastflag;
  if (t == 0) arr = atomicAdd((unsigned*)(ws + OFF_CNT) + pair, 1u);
  __syncthreads();
  if (arr == 15) {
    float sum = __uint_as_float(atomicOr(&cmu[t], 0u)) +
                __uint_as_float(atomicOr(&cmu[t + 256], 0u));
#pragma unroll
    for (int off = 32; off; off >>= 1) sum += __shfl_xor(sum, off);
    if (lane == 0) red[wv] = sum;
    if (t == 0) lastflag = 0;
    __syncthreads();
    if (t == 0) {
      float tot = red[0] + red[1] + red[2] + red[3];
      float loss = -logf(tot * (1.0f / 512.0f) + 1e-5f);
      atomicExch((unsigned*)(ws + OFF_PL) + pair, __float_as_uint(loss));
      __threadfence();
      unsigned d = atomicAdd((unsigned*)(ws + OFF_ALL), 1u);
      if (d == PAIRS - 1) lastflag = 1;
    }
    __syncthreads();
    if (lastflag && t < 32) {          // parallel 20-loss readback
      float v = (t < PAIRS)
                    ? __uint_as_float(atomicOr((unsigned*)(ws + OFF_PL) + t, 0u))
                    : 0.f;
#pragma unroll
      for (int off = 16; off; off >>= 1) v += __shfl_xor(v, off);
      if (t == 0) out[0] = v * (1.0f / (float)PAIRS);
    }
  }
}

extern "C" void kernel_launch(void* const* d_in, const int* in_sizes, int n_in,
                              void* d_out, int out_size, void* d_ws, size_t ws_size,
                              hipStream_t stream) {
  const float* x = (const float*)d_in[0];
  const float* y = (const float*)d_in[1];
  const int* hi = (const int*)d_in[2];
  const int* wi = (const int*)d_in[3];
  const int* di = (const int*)d_in[4];
  float* ws = (float*)d_ws;
  float* out = (float*)d_out;

  hipMemsetAsync(ws + OFF_CM, 0, ZERO_N * sizeof(float), stream);
  k_gather<<<1920, 256, 0, stream>>>(x, y, hi, wi, di, ws);
  k_norm2<<<320, 256, 0, stream>>>(ws);
  k_main<<<PAIRS * 16, 256, 0, stream>>>(ws, out);
}